// Round 1
// baseline (1191.661 us; speedup 1.0000x reference)
//
#include <hip/hip_runtime.h>
#include <math.h>

#define DIM 1024
#define THREE_DIM 3072
#define INNER 4096
#define NTOK 4096
#define NPAIR 8192
#define NEXP 8
#define MAXMB 72   // sum ceil(cnt_e/128) <= 8192/128 + 8

typedef __attribute__((ext_vector_type(8))) short bf16x8;
typedef __attribute__((ext_vector_type(4))) float f32x4;

__device__ __forceinline__ unsigned short f2bf(float f){
    unsigned int x = __float_as_uint(f);
    unsigned int r = x + 0x7fffu + ((x >> 16) & 1u);   // RNE, no NaN inputs expected
    return (unsigned short)(r >> 16);
}

// ---------------- LayerNorm (fp32 in, fp32 and/or bf16 out) ----------------
template<int WRITE_BF>
__global__ __launch_bounds__(256)
void ln_kernel(const float* __restrict__ X, const float* __restrict__ g,
               const float* __restrict__ b, float* __restrict__ outF,
               unsigned short* __restrict__ outB)
{
    int row = blockIdx.x;
    int t = threadIdx.x;
    const float4 v = *((const float4*)(X + (size_t)row*DIM) + t);
    float s = v.x + v.y + v.z + v.w;
    #pragma unroll
    for (int m = 1; m < 64; m <<= 1) s += __shfl_xor(s, m, 64);
    __shared__ float red[8];
    int wid = t >> 6, lane = t & 63;
    if (lane == 0) red[wid] = s;
    __syncthreads();
    float mu = (red[0]+red[1]+red[2]+red[3]) * (1.0f/DIM);
    float dx = v.x-mu, dy = v.y-mu, dz = v.z-mu, dw = v.w-mu;
    float s2 = dx*dx + dy*dy + dz*dz + dw*dw;
    #pragma unroll
    for (int m = 1; m < 64; m <<= 1) s2 += __shfl_xor(s2, m, 64);
    if (lane == 0) red[4+wid] = s2;
    __syncthreads();
    float var = (red[4]+red[5]+red[6]+red[7]) * (1.0f/DIM);
    float inv = rsqrtf(var + 1e-5f);
    const float4 gg = *((const float4*)g + t);
    const float4 bb = *((const float4*)b + t);
    float y0 = dx*inv*gg.x + bb.x;
    float y1 = dy*inv*gg.y + bb.y;
    float y2 = dz*inv*gg.z + bb.z;
    float y3 = dw*inv*gg.w + bb.w;
    if (outF){
        float4 o; o.x=y0; o.y=y1; o.z=y2; o.w=y3;
        *((float4*)(outF + (size_t)row*DIM) + t) = o;
    }
    if (WRITE_BF){
        ushort4 u; u.x=f2bf(y0); u.y=f2bf(y1); u.z=f2bf(y2); u.w=f2bf(y3);
        *((ushort4*)(outB + (size_t)row*DIM) + t) = u;
    }
}

// ---------------- fp32 SGEMM: C[M,N] = A[M,K] @ B[K,N]  (B row-major) ------
// MODE 0: plain store.  MODE 1: C = acc + bias[col] + resid[row,col]
template<int MODE>
__global__ __launch_bounds__(256)
void sgemm(const float* __restrict__ A, const float* __restrict__ B,
           float* __restrict__ C, int M, int N, int K,
           const float* __restrict__ bias, const float* __restrict__ resid)
{
    __shared__ float As[16][132];   // stored transposed: As[k][m]
    __shared__ float Bs[16][132];
    int t = threadIdx.x;
    int tm = t >> 4, tn = t & 15;
    int m0 = blockIdx.y * 128, n0 = blockIdx.x * 128;
    float acc[8][8];
    #pragma unroll
    for (int i = 0; i < 8; ++i)
        #pragma unroll
        for (int j = 0; j < 8; ++j) acc[i][j] = 0.f;

    for (int k0 = 0; k0 < K; k0 += 16){
        __syncthreads();
        #pragma unroll
        for (int it = 0; it < 2; ++it){
            int c = t + it*256;
            int ar = c >> 2, aq = (c & 3) << 2;
            float4 av = *(const float4*)(A + (size_t)(m0+ar)*K + k0 + aq);
            As[aq+0][ar] = av.x; As[aq+1][ar] = av.y;
            As[aq+2][ar] = av.z; As[aq+3][ar] = av.w;
            int br = c >> 5, bq = (c & 31) << 2;
            *(float4*)&Bs[br][bq] = *(const float4*)(B + (size_t)(k0+br)*N + n0 + bq);
        }
        __syncthreads();
        #pragma unroll
        for (int k = 0; k < 16; ++k){
            float a[8], bb[8];
            *(float4*)&a[0]  = *(const float4*)&As[k][tm*8];
            *(float4*)&a[4]  = *(const float4*)&As[k][tm*8+4];
            *(float4*)&bb[0] = *(const float4*)&Bs[k][tn*8];
            *(float4*)&bb[4] = *(const float4*)&Bs[k][tn*8+4];
            #pragma unroll
            for (int i = 0; i < 8; ++i)
                #pragma unroll
                for (int j = 0; j < 8; ++j)
                    acc[i][j] = fmaf(a[i], bb[j], acc[i][j]);
        }
    }
    #pragma unroll
    for (int i = 0; i < 8; ++i){
        int row = m0 + tm*8 + i;
        float* crow = C + (size_t)row*N + n0 + tn*8;
        if (MODE == 0){
            float4 o0, o1;
            o0.x=acc[i][0]; o0.y=acc[i][1]; o0.z=acc[i][2]; o0.w=acc[i][3];
            o1.x=acc[i][4]; o1.y=acc[i][5]; o1.z=acc[i][6]; o1.w=acc[i][7];
            *(float4*)crow = o0; *(float4*)(crow+4) = o1;
        } else {
            const float* rrow = resid + (size_t)row*N + n0 + tn*8;
            const float* brow = bias + n0 + tn*8;
            float4 r0 = *(const float4*)rrow, r1 = *(const float4*)(rrow+4);
            float4 b0 = *(const float4*)brow, b1v = *(const float4*)(brow+4);
            float4 o0, o1;
            o0.x = acc[i][0] + b0.x + r0.x;  o0.y = acc[i][1] + b0.y + r0.y;
            o0.z = acc[i][2] + b0.z + r0.z;  o0.w = acc[i][3] + b0.w + r0.w;
            o1.x = acc[i][4] + b1v.x + r1.x; o1.y = acc[i][5] + b1v.y + r1.y;
            o1.z = acc[i][6] + b1v.z + r1.z; o1.w = acc[i][7] + b1v.w + r1.w;
            *(float4*)crow = o0; *(float4*)(crow+4) = o1;
        }
    }
}

// ---------------- fp32 flash attention, 64x64 tiles ----------------
// qkv: [4096][3072] fp32 (q|k|v), head h at col h*64. O: [4096][1024] fp32.
__global__ __launch_bounds__(256)
void attn_kernel(const float* __restrict__ qkv, float* __restrict__ O,
                 const float* __restrict__ threshp)
{
    __shared__ float Qs[64][68];
    __shared__ float KP[64][68];   // K^T during S-phase, then P (probs)
    __shared__ float Vs[64][68];
    __shared__ float m_s[64], l_s[64];
    int t = threadIdx.x;
    int qt = blockIdx.x, hh = blockIdx.y, bb = blockIdx.z;
    int rg = t >> 4, jg = t & 15;
    float thresh = threshp[0];
    int qrow0 = bb*1024 + qt*64;
    #pragma unroll
    for (int it = 0; it < 4; ++it){
        int c = t + it*256;
        int r = c >> 4, q = (c & 15) << 2;
        *(float4*)&Qs[r][q] = *(const float4*)(qkv + (size_t)(qrow0+r)*3072 + hh*64 + q);
    }
    if (t < 64){ m_s[t] = -INFINITY; l_s[t] = 0.f; }
    float accv[4][4];
    #pragma unroll
    for (int i = 0; i < 4; ++i)
        #pragma unroll
        for (int j = 0; j < 4; ++j) accv[i][j] = 0.f;
    const float scale = 0.125f;

    for (int kt = 0; kt < 16; ++kt){
        __syncthreads();
        int krow0 = bb*1024 + kt*64;
        #pragma unroll
        for (int it = 0; it < 4; ++it){
            int c = t + it*256;
            int r = c >> 4, q = (c & 15) << 2;
            const float* srcK = qkv + (size_t)(krow0+r)*3072 + 1024 + hh*64 + q;
            float4 k4 = *(const float4*)srcK;
            KP[q+0][r] = k4.x; KP[q+1][r] = k4.y; KP[q+2][r] = k4.z; KP[q+3][r] = k4.w;
            *(float4*)&Vs[r][q] = *(const float4*)(srcK + 1024);
        }
        __syncthreads();
        float sv[4][4];
        #pragma unroll
        for (int i = 0; i < 4; ++i)
            #pragma unroll
            for (int j = 0; j < 4; ++j) sv[i][j] = 0.f;
        #pragma unroll
        for (int kk = 0; kk < 64; kk += 4){
            float qv[4][4], kv[4][4];
            #pragma unroll
            for (int ri = 0; ri < 4; ++ri){
                float4 tmp = *(const float4*)&Qs[rg*4+ri][kk];
                qv[ri][0]=tmp.x; qv[ri][1]=tmp.y; qv[ri][2]=tmp.z; qv[ri][3]=tmp.w;
            }
            #pragma unroll
            for (int kx = 0; kx < 4; ++kx){
                float4 tmp = *(const float4*)&KP[kk+kx][jg*4];
                kv[kx][0]=tmp.x; kv[kx][1]=tmp.y; kv[kx][2]=tmp.z; kv[kx][3]=tmp.w;
            }
            #pragma unroll
            for (int ri = 0; ri < 4; ++ri)
                #pragma unroll
                for (int ji = 0; ji < 4; ++ji)
                    #pragma unroll
                    for (int kx = 0; kx < 4; ++kx)
                        sv[ri][ji] = fmaf(qv[ri][kx], kv[kx][ji], sv[ri][ji]);
        }
        __syncthreads();   // everyone done reading KP as K^T
        float tmax[4];
        #pragma unroll
        for (int ri = 0; ri < 4; ++ri){
            float mx = -INFINITY;
            #pragma unroll
            for (int ji = 0; ji < 4; ++ji){
                float s = sv[ri][ji] * scale;
                s = (s < thresh) ? -1e9f : s;
                sv[ri][ji] = s;
                mx = fmaxf(mx, s);
            }
            tmax[ri] = mx;
        }
        #pragma unroll
        for (int m = 1; m < 16; m <<= 1)
            #pragma unroll
            for (int ri = 0; ri < 4; ++ri)
                tmax[ri] = fmaxf(tmax[ri], __shfl_xor(tmax[ri], m, 64));
        float mnew[4], fac[4], rsum[4];
        #pragma unroll
        for (int ri = 0; ri < 4; ++ri){
            int row = rg*4+ri;
            float mo = m_s[row];
            float mn = fmaxf(mo, tmax[ri]);
            mnew[ri] = mn; fac[ri] = __expf(mo - mn);
        }
        #pragma unroll
        for (int ri = 0; ri < 4; ++ri){
            float ss = 0.f;
            #pragma unroll
            for (int ji = 0; ji < 4; ++ji){
                float p = __expf(sv[ri][ji] - mnew[ri]);
                KP[rg*4+ri][jg*4+ji] = p;
                ss += p;
            }
            rsum[ri] = ss;
        }
        #pragma unroll
        for (int m = 1; m < 16; m <<= 1)
            #pragma unroll
            for (int ri = 0; ri < 4; ++ri)
                rsum[ri] += __shfl_xor(rsum[ri], m, 64);
        if (jg == 0){
            #pragma unroll
            for (int ri = 0; ri < 4; ++ri){
                int row = rg*4+ri;
                l_s[row] = l_s[row]*fac[ri] + rsum[ri];
                m_s[row] = mnew[ri];
            }
        }
        #pragma unroll
        for (int ri = 0; ri < 4; ++ri)
            #pragma unroll
            for (int di = 0; di < 4; ++di) accv[ri][di] *= fac[ri];
        // PV: same-wave DS ordering guarantees P visibility (writers=readers' wave)
        #pragma unroll
        for (int j4 = 0; j4 < 64; j4 += 4){
            float pv[4][4], vv[4][4];
            #pragma unroll
            for (int ri = 0; ri < 4; ++ri){
                float4 tmp = *(const float4*)&KP[rg*4+ri][j4];
                pv[ri][0]=tmp.x; pv[ri][1]=tmp.y; pv[ri][2]=tmp.z; pv[ri][3]=tmp.w;
            }
            #pragma unroll
            for (int jj = 0; jj < 4; ++jj){
                float4 tmp = *(const float4*)&Vs[j4+jj][jg*4];
                vv[jj][0]=tmp.x; vv[jj][1]=tmp.y; vv[jj][2]=tmp.z; vv[jj][3]=tmp.w;
            }
            #pragma unroll
            for (int ri = 0; ri < 4; ++ri)
                #pragma unroll
                for (int jj = 0; jj < 4; ++jj)
                    #pragma unroll
                    for (int di = 0; di < 4; ++di)
                        accv[ri][di] = fmaf(pv[ri][jj], vv[jj][di], accv[ri][di]);
        }
    }
    #pragma unroll
    for (int ri = 0; ri < 4; ++ri){
        int row = rg*4+ri;
        float inv = 1.0f / l_s[row];
        float4 o4;
        o4.x = accv[ri][0]*inv; o4.y = accv[ri][1]*inv;
        o4.z = accv[ri][2]*inv; o4.w = accv[ri][3]*inv;
        *(float4*)(O + (size_t)(qrow0+row)*1024 + hh*64 + jg*4) = o4;
    }
}

// ---------------- gate: logits, softmax probs, top-2 ----------------
__global__ __launch_bounds__(64)
void gate_kernel(const float* __restrict__ h2, const float* __restrict__ gw,
                 float* __restrict__ probs, int* __restrict__ top_i,
                 float* __restrict__ top_w)
{
    int tk = blockIdx.x;
    int lane = threadIdx.x;
    const float* hr = h2 + (size_t)tk*DIM;
    float acc[8];
    #pragma unroll
    for (int e = 0; e < 8; ++e) acc[e] = 0.f;
    for (int d = lane; d < DIM; d += 64){
        float hv = hr[d];
        const float* grow = gw + d*8;
        #pragma unroll
        for (int e = 0; e < 8; ++e) acc[e] = fmaf(hv, grow[e], acc[e]);
    }
    #pragma unroll
    for (int m = 1; m < 64; m <<= 1)
        #pragma unroll
        for (int e = 0; e < 8; ++e) acc[e] += __shfl_xor(acc[e], m, 64);
    if (lane == 0){
        float mx = acc[0];
        #pragma unroll
        for (int e = 1; e < 8; ++e) mx = fmaxf(mx, acc[e]);
        float p[8], s = 0.f;
        #pragma unroll
        for (int e = 0; e < 8; ++e){ p[e] = __expf(acc[e]-mx); s += p[e]; }
        float invs = 1.f/s;
        #pragma unroll
        for (int e = 0; e < 8; ++e) probs[(size_t)tk*8+e] = p[e]*invs;
        int i0 = 0; float v0 = acc[0];
        #pragma unroll
        for (int e = 1; e < 8; ++e) if (acc[e] > v0){ v0 = acc[e]; i0 = e; }
        int i1 = -1; float v1 = -INFINITY;
        #pragma unroll
        for (int e = 0; e < 8; ++e) if (e != i0 && acc[e] > v1){ v1 = acc[e]; i1 = e; }
        float w0 = 1.f/(1.f + __expf(v1 - v0));
        top_i[tk*2]   = i0; top_i[tk*2+1] = i1;
        top_w[tk*2]   = w0; top_w[tk*2+1] = 1.f - w0;
    }
}

// ---------------- aux loss ----------------
__global__ __launch_bounds__(256)
void aux_kernel(const float* __restrict__ probs, float* __restrict__ dout)
{
    int t = threadIdx.x;
    float acc[8];
    #pragma unroll
    for (int e = 0; e < 8; ++e) acc[e] = 0.f;
    for (int r = t; r < NTOK; r += 256){
        const float* pr = probs + (size_t)r*8;
        #pragma unroll
        for (int e = 0; e < 8; ++e) acc[e] += pr[e];
    }
    #pragma unroll
    for (int m = 1; m < 64; m <<= 1)
        #pragma unroll
        for (int e = 0; e < 8; ++e) acc[e] += __shfl_xor(acc[e], m, 64);
    __shared__ float red[4][8];
    int wid = t >> 6, lane = t & 63;
    if (lane == 0)
        for (int e = 0; e < 8; ++e) red[wid][e] = acc[e];
    __syncthreads();
    if (t == 0){
        float aux = 0.f;
        for (int e = 0; e < 8; ++e){
            float S = red[0][e]+red[1][e]+red[2][e]+red[3][e];
            aux += S*S;
        }
        dout[(size_t)NTOK*DIM] = aux * (8.0f/NTOK);
    }
}

// ---------------- routing: expert-grouped, 128-padded compaction ----------
__global__ __launch_bounds__(512)
void routing_kernel(const int* __restrict__ topi, int* __restrict__ perm,
                    int* __restrict__ mblk_e)
{
    __shared__ int cnt[8];
    __shared__ int obase[8];
    int t = threadIdx.x, w = t >> 6, lane = t & 63;
    int c = 0;
    for (int i0 = 0; i0 < NPAIR; i0 += 64){
        int e = topi[i0 + lane];
        c += (e == w) ? 1 : 0;
    }
    #pragma unroll
    for (int m = 1; m < 64; m <<= 1) c += __shfl_xor(c, m, 64);
    if (lane == 0) cnt[w] = c;
    __syncthreads();
    if (t == 0){
        int mb = 0;
        for (int e = 0; e < 8; ++e){
            obase[e] = mb*128;
            int nb = (cnt[e] + 127) >> 7;
            for (int k = 0; k < nb; ++k) mblk_e[mb++] = e;
        }
        for (; mb < MAXMB; ++mb) mblk_e[mb] = -1;
    }
    __syncthreads();
    for (int i = t; i < MAXMB*128; i += 512) perm[i] = -1;
    __syncthreads();
    int base = obase[w];
    for (int i0 = 0; i0 < NPAIR; i0 += 64){
        int p = i0 + lane;
        int e = topi[p];
        bool mt = (e == w);
        unsigned long long mk = __ballot(mt);
        int rank = __popcll(mk & ((1ull << lane) - 1ull));
        if (mt) perm[base + rank] = p;
        base += __popcll(mk);
    }
}

// ---------------- grouped bf16 MFMA GEMM for MoE ----------------
// MODE 2: act[mbrow, n] = gelu(h2bf[tok] @ w1T[e] + b1[e])  (bf16 out)
// MODE 3: atomicAdd(d_out[tok, n], top_w * (act[mbrow] @ w2T[e] + b2[e]))
template<int MODE>
__global__ __launch_bounds__(256)
void gemm_moe(const unsigned short* __restrict__ Abase,
              const unsigned short* __restrict__ BTbase,
              int K, int N, int lda,
              const int* __restrict__ perm, const int* __restrict__ mblk_e,
              const float* __restrict__ bias,
              unsigned short* __restrict__ actout,
              const float* __restrict__ topw, float* __restrict__ dout)
{
    int mb = blockIdx.y;
    int e = mblk_e[mb];
    if (e < 0) return;
    __shared__ __align__(16) unsigned short As[128*40];
    __shared__ __align__(16) unsigned short Bs[128*40];
    __shared__ int permL[128];
    int t = threadIdx.x;
    if (t < 128) permL[t] = perm[mb*128 + t];
    __syncthreads();
    int lane = t & 63, wid = t >> 6, wm = wid >> 1, wn = wid & 1;
    int n0 = blockIdx.x * 128;
    const unsigned short* BT = BTbase + (size_t)e * (size_t)N * (size_t)K;
    f32x4 acc[4][4];
    #pragma unroll
    for (int mi = 0; mi < 4; ++mi)
        #pragma unroll
        for (int ni = 0; ni < 4; ++ni)
            #pragma unroll
            for (int q = 0; q < 4; ++q) acc[mi][ni][q] = 0.f;

    for (int k0 = 0; k0 < K; k0 += 32){
        __syncthreads();
        #pragma unroll
        for (int it = 0; it < 2; ++it){
            int c = t + it*256;
            int r = c >> 2, q = c & 3;
            size_t arow;
            if (MODE == 2){
                int p = permL[r];
                arow = (p >= 0) ? (size_t)(p >> 1) : 0;
            } else {
                arow = (size_t)(mb*128 + r);
            }
            *(uint4*)&As[r*40 + q*8] = *(const uint4*)(Abase + arow*lda + k0 + q*8);
            *(uint4*)&Bs[r*40 + q*8] = *(const uint4*)(BT + (size_t)(n0+r)*K + k0 + q*8);
        }
        __syncthreads();
        bf16x8 af[4], bfr[4];
        #pragma unroll
        for (int mi = 0; mi < 4; ++mi)
            af[mi] = *(const bf16x8*)&As[(wm*64 + mi*16 + (lane & 15))*40 + (lane >> 4)*8];
        #pragma unroll
        for (int ni = 0; ni < 4; ++ni)
            bfr[ni] = *(const bf16x8*)&Bs[(wn*64 + ni*16 + (lane & 15))*40 + (lane >> 4)*8];
        #pragma unroll
        for (int mi = 0; mi < 4; ++mi)
            #pragma unroll
            for (int ni = 0; ni < 4; ++ni)
                acc[mi][ni] = __builtin_amdgcn_mfma_f32_16x16x32_bf16(
                                  af[mi], bfr[ni], acc[mi][ni], 0, 0, 0);
    }
    // epilogue: row = (lane>>4)*4 + reg, col = lane&15   [guide-verified C/D map]
    #pragma unroll
    for (int mi = 0; mi < 4; ++mi){
        #pragma unroll
        for (int ni = 0; ni < 4; ++ni){
            int ccol = n0 + wn*64 + ni*16 + (lane & 15);
            float bv = bias[(size_t)e*N + ccol];
            #pragma unroll
            for (int j = 0; j < 4; ++j){
                int rloc = wm*64 + mi*16 + (lane >> 4)*4 + j;
                float v = acc[mi][ni][j];
                if (MODE == 2){
                    float gx = v + bv;
                    float gl = 0.5f * gx * (1.0f + erff(gx * 0.70710678118f));
                    actout[(size_t)(mb*128 + rloc)*N + ccol] = f2bf(gl);
                } else {
                    int p = permL[rloc];
                    if (p >= 0){
                        float val = (v + bv) * topw[p];
                        atomicAdd(&dout[(size_t)(p >> 1)*N + ccol], val);
                    }
                }
            }
        }
    }
}

// ---------------- transpose + cast fp32 -> bf16: WT[n][k] = W[k][n] --------
__global__ __launch_bounds__(256)
void transp_cast(const float* __restrict__ W, unsigned short* __restrict__ WT,
                 int K, int N)
{
    __shared__ float tile[32][33];
    size_t base = (size_t)blockIdx.z * (size_t)K * (size_t)N;
    const float* Wp = W + base;
    unsigned short* Tp = WT + base;
    int t = threadIdx.x;
    int r = t >> 3, c4 = (t & 7) << 2;
    int n0 = blockIdx.x << 5, k0 = blockIdx.y << 5;
    float4 v = *(const float4*)(Wp + (size_t)(k0+r)*N + n0 + c4);
    tile[r][c4+0] = v.x; tile[r][c4+1] = v.y;
    tile[r][c4+2] = v.z; tile[r][c4+3] = v.w;
    __syncthreads();
    ushort4 u;
    u.x = f2bf(tile[c4+0][r]);
    u.y = f2bf(tile[c4+1][r]);
    u.z = f2bf(tile[c4+2][r]);
    u.w = f2bf(tile[c4+3][r]);
    *(ushort4*)(Tp + (size_t)(n0+r)*K + k0 + c4) = u;
}

// ---------------- launch ----------------
extern "C" void kernel_launch(void* const* d_in, const int* in_sizes, int n_in,
                              void* d_out, int out_size, void* d_ws, size_t ws_size,
                              hipStream_t stream)
{
    const float* x      = (const float*)d_in[0];
    const float* qkv_w  = (const float*)d_in[1];
    const float* out_w  = (const float*)d_in[2];
    const float* out_b  = (const float*)d_in[3];
    const float* thresh = (const float*)d_in[4];
    const float* ln1_g  = (const float*)d_in[5];
    const float* ln1_b  = (const float*)d_in[6];
    const float* ln2_g  = (const float*)d_in[7];
    const float* ln2_b  = (const float*)d_in[8];
    const float* gate_w = (const float*)d_in[9];
    const float* w1     = (const float*)d_in[10];
    const float* b1     = (const float*)d_in[11];
    const float* w2     = (const float*)d_in[12];
    const float* b2     = (const float*)d_in[13];
    float* out = (float*)d_out;
    char* ws = (char*)d_ws;

    const size_t MB = (size_t)1 << 20;
    float* h             = (float*)(ws);                    // 16 MB
    float* qkvb          = (float*)(ws + 16*MB);            // 48 MB
    float* o             = (float*)(ws + 64*MB);            // 16 MB
    float* h2            = (float*)(ws + 80*MB);            // 16 MB
    unsigned short* h2bf = (unsigned short*)(ws + 96*MB);   // 8 MB
    unsigned short* w1T  = (unsigned short*)(ws + 104*MB);  // 64 MB
    unsigned short* w2T  = (unsigned short*)(ws + 168*MB);  // 64 MB
    unsigned short* act  = (unsigned short*)(ws + 232*MB);  // 75.5 MB (9216x4096 bf16)
    float* probs         = (float*)(ws + 308*MB);           // 128 KB
    int*   top_i         = (int*)(ws + 308*MB + 131072);    // 32 KB
    float* top_w         = (float*)(ws + 308*MB + 131072 + 32768);
    int*   perm          = (int*)(ws + 308*MB + 131072 + 65536);   // 36 KB
    int*   mblk          = (int*)(ws + 308*MB + 131072 + 65536 + 40960);

    // MoE weight transpose+cast (independent; issue first)
    transp_cast<<<dim3(INNER/32, DIM/32, NEXP), 256, 0, stream>>>(w1, w1T, DIM, INNER);
    transp_cast<<<dim3(DIM/32, INNER/32, NEXP), 256, 0, stream>>>(w2, w2T, INNER, DIM);

    ln_kernel<0><<<NTOK, 256, 0, stream>>>(x, ln1_g, ln1_b, h, nullptr);
    sgemm<0><<<dim3(THREE_DIM/128, NTOK/128), 256, 0, stream>>>(
        h, qkv_w, qkvb, NTOK, THREE_DIM, DIM, nullptr, nullptr);
    attn_kernel<<<dim3(16, 16, 4), 256, 0, stream>>>(qkvb, o, thresh);
    sgemm<1><<<dim3(DIM/128, NTOK/128), 256, 0, stream>>>(
        o, out_w, out, NTOK, DIM, DIM, out_b, x);
    ln_kernel<1><<<NTOK, 256, 0, stream>>>(out, ln2_g, ln2_b, h2, h2bf);
    gate_kernel<<<NTOK, 64, 0, stream>>>(h2, gate_w, probs, top_i, top_w);
    aux_kernel<<<1, 256, 0, stream>>>(probs, out);
    routing_kernel<<<1, 512, 0, stream>>>(top_i, perm, mblk);
    gemm_moe<2><<<dim3(INNER/128, MAXMB), 256, 0, stream>>>(
        h2bf, w1T, DIM, INNER, DIM, perm, mblk, b1, act, nullptr, nullptr);
    gemm_moe<3><<<dim3(DIM/128, MAXMB), 256, 0, stream>>>(
        act, w2T, INNER, DIM, INNER, perm, mblk, b2, nullptr, top_w, out);
}